// Round 1
// baseline (1627.688 us; speedup 1.0000x reference)
//
#include <hip/hip_runtime.h>
#include <cstdint>

#define T_TOK   16384
#define DM      1024
#define DFF     4096
#define NE      8

typedef unsigned short u16;
typedef __bf16 bf16x8 __attribute__((ext_vector_type(8)));
typedef float  f32x4  __attribute__((ext_vector_type(4)));

__device__ __forceinline__ u16 f2bf(float f) {
  unsigned u = __float_as_uint(f);
  u = u + 0x7FFFu + ((u >> 16) & 1u);
  return (u16)(u >> 16);
}

__device__ __forceinline__ void async_copy16(void* lds, const void* g) {
  __builtin_amdgcn_global_load_lds(
      (const __attribute__((address_space(1))) unsigned int*)g,
      (__attribute__((address_space(3))) unsigned int*)lds, 16, 0, 0);
}

// ---------------- converts ----------------
__global__ __launch_bounds__(256) void convert_x_kernel(
    const float* __restrict__ x, u16* __restrict__ xb) {
  int i = blockIdx.x * 256 + threadIdx.x;           // T*DM/4 threads
  float4 v = ((const float4*)x)[i];
  uint2 o;
  o.x = (unsigned)f2bf(v.x) | ((unsigned)f2bf(v.y) << 16);
  o.y = (unsigned)f2bf(v.z) | ((unsigned)f2bf(v.w) << 16);
  ((uint2*)xb)[i] = o;
}

// in: fp32 [E][R][C] -> out: bf16 [E][C][R]
__global__ __launch_bounds__(256) void transpose_convert_kernel(
    const float* __restrict__ in, u16* __restrict__ out, int R, int C) {
  __shared__ float tile[32][33];
  int e = blockIdx.z;
  int r0 = blockIdx.y * 32, c0 = blockIdx.x * 32;
  int tx = threadIdx.x, ty = threadIdx.y;           // (32, 8)
  const float* src = in + (size_t)e * R * C;
  u16* dst = out + (size_t)e * R * C;
  #pragma unroll
  for (int i = 0; i < 32; i += 8)
    tile[ty + i][tx] = src[(size_t)(r0 + ty + i) * C + (c0 + tx)];
  __syncthreads();
  #pragma unroll
  for (int i = 0; i < 32; i += 8)
    dst[(size_t)(c0 + ty + i) * R + (r0 + tx)] = f2bf(tile[tx][ty + i]);
}

// ---------------- router ----------------
__global__ __launch_bounds__(256) void router_kernel(
    const float* __restrict__ x, const float* __restrict__ wr,
    int* __restrict__ tok_e, float* __restrict__ tok_w,
    int* __restrict__ counts, float* __restrict__ psum) {
  __shared__ float ps[NE];
  __shared__ int   pc[NE];
  int tid = threadIdx.x, wave = tid >> 6, lane = tid & 63;
  if (tid < NE) { ps[tid] = 0.f; pc[tid] = 0; }
  __syncthreads();

  int t = blockIdx.x * 4 + wave;
  const float* xrow = x + (size_t)t * DM;
  float acc[NE];
  #pragma unroll
  for (int e = 0; e < NE; ++e) acc[e] = 0.f;
  for (int j = 0; j < DM / 64; ++j) {
    float xv = xrow[j * 64 + lane];
    const float* w = wr + (size_t)(j * 64 + lane) * NE;
    #pragma unroll
    for (int e = 0; e < NE; ++e) acc[e] += xv * w[e];
  }
  #pragma unroll
  for (int m = 1; m < 64; m <<= 1) {
    #pragma unroll
    for (int e = 0; e < NE; ++e) acc[e] += __shfl_xor(acc[e], m, 64);
  }
  if (lane == 0) {
    float mx = acc[0];
    #pragma unroll
    for (int e = 1; e < NE; ++e) mx = fmaxf(mx, acc[e]);
    float p[NE], s = 0.f;
    #pragma unroll
    for (int e = 0; e < NE; ++e) { p[e] = expf(acc[e] - mx); s += p[e]; }
    float inv = 1.f / s;
    int i1 = 0; float b1v = p[0];
    #pragma unroll
    for (int e = 1; e < NE; ++e) if (p[e] > b1v) { b1v = p[e]; i1 = e; }
    int i2 = -1; float b2v = -1.f;
    #pragma unroll
    for (int e = 0; e < NE; ++e) if (e != i1 && p[e] > b2v) { b2v = p[e]; i2 = e; }
    float wsum = b1v + b2v;
    tok_e[2 * t]     = i1;  tok_e[2 * t + 1] = i2;
    tok_w[2 * t]     = b1v / wsum;
    tok_w[2 * t + 1] = b2v / wsum;
    atomicAdd(&pc[i1], 1); atomicAdd(&pc[i2], 1);
    #pragma unroll
    for (int e = 0; e < NE; ++e) atomicAdd(&ps[e], p[e] * inv);
  }
  __syncthreads();
  if (tid < NE) { atomicAdd(&counts[tid], pc[tid]); atomicAdd(&psum[tid], ps[tid]); }
}

__global__ void scan_kernel(const int* __restrict__ counts, int* __restrict__ offsets) {
  if (threadIdx.x == 0) {
    int r = 0;
    for (int e = 0; e < NE; ++e) { offsets[e] = r; r += counts[e]; }
  }
}

__global__ __launch_bounds__(256) void build_lists_kernel(
    const int* __restrict__ tok_e, const float* __restrict__ tok_w,
    const int* __restrict__ offsets, int* __restrict__ fill,
    int* __restrict__ rowlist, float* __restrict__ roww) {
  int t = blockIdx.x * 256 + threadIdx.x;
  #pragma unroll
  for (int s = 0; s < 2; ++s) {
    int e = tok_e[2 * t + s];
    int pos = atomicAdd(&fill[e], 1);
    int idx = offsets[e] + pos;
    rowlist[idx] = t;
    roww[idx] = tok_w[2 * t + s];
  }
}

// ---------------- expert GEMMs ----------------
// PASS 1: A = gathered xb rows (K=1024), B = W1T [n][k], out: h=gelu(AB+b1) bf16
// PASS 2: A = h rows (contig, K=4096), B = W2T [n][k], out: atomicAdd(out, w*(AB+b2))
template <int PASS>
__global__ __launch_bounds__(256) void moe_gemm_kernel(
    const u16* __restrict__ Asrc, const u16* __restrict__ BT,
    const float* __restrict__ bias,
    const int* __restrict__ counts, const int* __restrict__ offsets,
    const int* __restrict__ rowlist, const float* __restrict__ roww,
    u16* __restrict__ Hout, float* __restrict__ Out) {
  constexpr int K = (PASS == 1) ? DM : DFF;
  constexpr int N = (PASS == 1) ? DFF : DM;

  const int e = blockIdx.z;
  const int cnt = counts[e];
  const int row0 = blockIdx.y * 128;
  if (row0 >= cnt) return;
  const int off = offsets[e];
  const int nb = blockIdx.x * 128;
  const int tid = threadIdx.x, wave = tid >> 6, lane = tid & 63;

  __shared__ u16 lsA[128 * 64];
  __shared__ u16 lsB[128 * 64];

  // staging: per thread 4 A-rows + 4 B-rows; lane -> (row = i*8+(lane>>3), chunk = lane&7)
  // pre-swizzled global chunk = (lane&7) ^ (lane>>3)  [linear LDS dest, inverse-swz source]
  const int sw = (((lane & 7) ^ (lane >> 3)) * 8);
  const u16* aPtr[4];
  const u16* bPtr[4];
  #pragma unroll
  for (int i = 0; i < 4; ++i) {
    int rowi = (wave * 4 + i) * 8 + (lane >> 3);   // 0..127
    int r = row0 + rowi;
    int rr = (r < cnt) ? r : (cnt - 1);
    int srcrow;
    if (PASS == 1) srcrow = rowlist[off + rr];
    else           srcrow = off + rr;
    aPtr[i] = Asrc + (size_t)srcrow * K + sw;
    bPtr[i] = BT + ((size_t)e * N + (nb + rowi)) * K + sw;
  }

  f32x4 acc[4][4];
  #pragma unroll
  for (int m = 0; m < 4; ++m)
    #pragma unroll
    for (int n = 0; n < 4; ++n) acc[m][n] = (f32x4){0.f, 0.f, 0.f, 0.f};

  const int wm = wave >> 1, wn = wave & 1;

  for (int kt = 0; kt < K; kt += 64) {
    #pragma unroll
    for (int i = 0; i < 4; ++i) {
      async_copy16(&lsA[(wave * 4 + i) * 512], aPtr[i] + kt);
      async_copy16(&lsB[(wave * 4 + i) * 512], bPtr[i] + kt);
    }
    __syncthreads();   // compiler drains vmcnt before s_barrier
    #pragma unroll
    for (int ks = 0; ks < 2; ++ks) {
      const int cbase = (((ks * 4 + (lane >> 4)) ^ (lane & 7)) * 8);
      bf16x8 af[4], bfr[4];
      #pragma unroll
      for (int m = 0; m < 4; ++m) {
        int rowA = wm * 64 + m * 16 + (lane & 15);
        af[m] = *(const bf16x8*)&lsA[rowA * 64 + cbase];
      }
      #pragma unroll
      for (int n = 0; n < 4; ++n) {
        int rowB = wn * 64 + n * 16 + (lane & 15);
        bfr[n] = *(const bf16x8*)&lsB[rowB * 64 + cbase];
      }
      #pragma unroll
      for (int m = 0; m < 4; ++m)
        #pragma unroll
        for (int n = 0; n < 4; ++n)
          acc[m][n] = __builtin_amdgcn_mfma_f32_16x16x32_bf16(af[m], bfr[n], acc[m][n], 0, 0, 0);
    }
    __syncthreads();
  }

  // epilogue: C/D layout col = lane&15, row = (lane>>4)*4 + reg (m89-verified)
  float bv[4];
  #pragma unroll
  for (int n = 0; n < 4; ++n)
    bv[n] = bias[e * N + nb + wn * 64 + n * 16 + (lane & 15)];

  if (PASS == 1) {
    #pragma unroll
    for (int m = 0; m < 4; ++m) {
      #pragma unroll
      for (int j = 0; j < 4; ++j) {
        int r = row0 + wm * 64 + m * 16 + (lane >> 4) * 4 + j;
        if (r < cnt) {
          size_t base = (size_t)(off + r) * DFF;
          #pragma unroll
          for (int n = 0; n < 4; ++n) {
            int c = nb + wn * 64 + n * 16 + (lane & 15);
            float v = acc[m][n][j] + bv[n];
            v = 0.5f * v * (1.f + erff(v * 0.70710678118654752f));  // exact GELU
            Hout[base + c] = f2bf(v);
          }
        }
      }
    }
  } else {
    #pragma unroll
    for (int m = 0; m < 4; ++m) {
      #pragma unroll
      for (int j = 0; j < 4; ++j) {
        int r = row0 + wm * 64 + m * 16 + (lane >> 4) * 4 + j;
        if (r < cnt) {
          int t = rowlist[off + r];
          float w = roww[off + r];
          size_t base = (size_t)t * DM;
          #pragma unroll
          for (int n = 0; n < 4; ++n) {
            int c = nb + wn * 64 + n * 16 + (lane & 15);
            atomicAdd(&Out[base + c], w * (acc[m][n][j] + bv[n]));
          }
        }
      }
    }
  }
}

__global__ void aux_kernel(const int* __restrict__ counts, const float* __restrict__ psum,
                           float* __restrict__ out_aux) {
  if (threadIdx.x == 0) {
    float s = 0.f;
    for (int e = 0; e < NE; ++e)
      s += ((float)counts[e] / (float)(2 * T_TOK)) * (psum[e] / (float)T_TOK);
    *out_aux = (float)NE * 0.01f * s;
  }
}

// ---------------- host ----------------
extern "C" void kernel_launch(void* const* d_in, const int* in_sizes, int n_in,
                              void* d_out, int out_size, void* d_ws, size_t ws_size,
                              hipStream_t stream) {
  const float* x  = (const float*)d_in[0];
  const float* wr = (const float*)d_in[1];
  const float* W1 = (const float*)d_in[2];
  const float* b1 = (const float*)d_in[3];
  const float* W2 = (const float*)d_in[4];
  const float* b2 = (const float*)d_in[5];
  float* out = (float*)d_out;
  char* ws = (char*)d_ws;

  // ws layout (needs ~417 MiB)
  int*   counts  = (int*)(ws + 0);
  int*   fill    = (int*)(ws + 32);
  float* psum    = (float*)(ws + 64);
  int*   offsets = (int*)(ws + 96);
  int*   tok_e   = (int*)(ws + 256);
  float* tok_w   = (float*)(ws + 256 + 131072);
  int*   rowlist = (int*)(ws + 256 + 2 * 131072);
  float* roww    = (float*)(ws + 256 + 3 * 131072);
  const size_t MiB = 1ull << 20;
  u16* xb  = (u16*)(ws + 1 * MiB);     // 32 MiB
  u16* W1T = (u16*)(ws + 33 * MiB);    // 64 MiB  [E][DFF][DM]
  u16* W2T = (u16*)(ws + 97 * MiB);    // 64 MiB  [E][DM][DFF]
  u16* h   = (u16*)(ws + 161 * MiB);   // 256 MiB [2T][DFF]

  hipMemsetAsync(ws, 0, 256, stream);
  hipMemsetAsync(d_out, 0, (size_t)out_size * sizeof(float), stream);

  convert_x_kernel<<<T_TOK * DM / 4 / 256, 256, 0, stream>>>(x, xb);
  transpose_convert_kernel<<<dim3(DFF / 32, DM / 32, NE), dim3(32, 8), 0, stream>>>(W1, W1T, DM, DFF);
  transpose_convert_kernel<<<dim3(DM / 32, DFF / 32, NE), dim3(32, 8), 0, stream>>>(W2, W2T, DFF, DM);
  router_kernel<<<T_TOK / 4, 256, 0, stream>>>(x, wr, tok_e, tok_w, counts, psum);
  scan_kernel<<<1, 64, 0, stream>>>(counts, offsets);
  build_lists_kernel<<<T_TOK / 256, 256, 0, stream>>>(tok_e, tok_w, offsets, fill, rowlist, roww);
  moe_gemm_kernel<1><<<dim3(DFF / 128, T_TOK / 128, NE), 256, 0, stream>>>(
      xb, W1T, b1, counts, offsets, rowlist, roww, h, nullptr);
  moe_gemm_kernel<2><<<dim3(DM / 128, T_TOK / 128, NE), 256, 0, stream>>>(
      h, W2T, b2, counts, offsets, rowlist, roww, nullptr, out);
  aux_kernel<<<1, 64, 0, stream>>>(counts, psum, out + (size_t)T_TOK * DM);
}